// Round 11
// baseline (294.748 us; speedup 1.0000x reference)
//
#include <hip/hip_runtime.h>
#include <hip/hip_bf16.h>

#define B_ 2
#define S_ 2048
#define E_ 1024
#define H_ 16
#define D_ 64
#define NE_ 8
#define TOKENS (B_*S_)   // 4096
#define QSCALE 0.18033688011112043f   // log2(e)/8, folded into Q

typedef __attribute__((ext_vector_type(8))) short bf16x8;
typedef __attribute__((ext_vector_type(4))) float f32x4;
typedef unsigned short u16;
typedef unsigned int u32;

#if __has_builtin(__builtin_amdgcn_exp2f)
#define EXP2(x) __builtin_amdgcn_exp2f(x)
#else
#define EXP2(x) exp2f(x)
#endif

__device__ __forceinline__ u16 f2bf(float f) {
    u32 u = __float_as_uint(f);
    u32 r = u + 0x7fffu + ((u >> 16) & 1u);
    return (u16)(r >> 16);
}
__device__ __forceinline__ float bf2f(u16 h) {
    return __uint_as_float(((u32)h) << 16);
}
__device__ __forceinline__ void gl2lds16(const void* g, void* l) {
    __builtin_amdgcn_global_load_lds(
        (__attribute__((address_space(1))) void*)(g),
        (__attribute__((address_space(3))) void*)(l), 16, 0, 0);
}
#define MFMA16(a,b,c) __builtin_amdgcn_mfma_f32_16x16x32_bf16(a,b,c,0,0,0)

// ---------------------------------------------------------------------------
// Fused fp32 -> bf16 conversion for all six tensors + RoPE table (one dispatch).
// Blocks 0..255: cos/sin table FIRST (sincos-heavy; overlaps the streaming
// blocks instead of straggling the tail). Blocks 256..16639: conversions.
// ---------------------------------------------------------------------------
__global__ void cvt_all_k(
    const float* __restrict__ x,  const float* __restrict__ qw,
    const float* __restrict__ kw, const float* __restrict__ vw,
    const float* __restrict__ fw, const float* __restrict__ ew,
    u16* __restrict__ xh,  u16* __restrict__ qwh, u16* __restrict__ kwh,
    u16* __restrict__ vwh, u16* __restrict__ fwh, u16* __restrict__ ewh,
    float2* __restrict__ tab)
{
    const int blk = blockIdx.x;
    if (blk < 256) {
        const int idx = blk * 256 + threadIdx.x;   // < 65536
        const int s = idx >> 5, d1 = idx & 31;
        const float inv = exp2f(-(float)d1 * 0.41524101186091903f);
        float sn, cs;
        sincosf((float)s * inv, &sn, &cs);
        tab[idx] = make_float2(cs, sn);
        return;
    }
    const int b2 = blk - 256;
    const float* s; u16* d; int off;
    if (b2 < 4096)      { s = x;  d = xh;  off = b2; }
    else if (b2 < 5120) { s = qw; d = qwh; off = b2 - 4096; }
    else if (b2 < 6144) { s = kw; d = kwh; off = b2 - 5120; }
    else if (b2 < 7168) { s = vw; d = vwh; off = b2 - 6144; }
    else if (b2 < 8192) { s = fw; d = fwh; off = b2 - 7168; }
    else                { s = ew; d = ewh; off = b2 - 8192; }
    const size_t i = (size_t)off * 256 + threadIdx.x;
    const float4 v = *(const float4*)(s + i * 4);
    ushort4 H = {f2bf(v.x), f2bf(v.y), f2bf(v.z), f2bf(v.w)};
    *(ushort4*)(d + i * 4) = H;
}

// ---------------------------------------------------------------------------
// Fused Q/K/V projection GEMM. 128x128 tile, BK=64 as two [128][32] half
// tiles. XCD swizzle: lin%8 = n0-column. 768 blocks @3/CU: full device.
// z<2: RoPE epilogue, head-major [b][h][s][d] bf16 (Q scaled by QSCALE).
// z=2: transposed store Vt[b][h][d][s].
// ---------------------------------------------------------------------------
__global__ __launch_bounds__(256,3) void gemm_qkv(
    const u16* __restrict__ Ah,
    const u16* __restrict__ qwh, const u16* __restrict__ kwh,
    const u16* __restrict__ vwh,
    const float* __restrict__ q_b, const float* __restrict__ k_b,
    const float* __restrict__ v_b,
    const float2* __restrict__ tab,
    u16* __restrict__ Qhb, u16* __restrict__ Khb, u16* __restrict__ Vtb)
{
    __shared__ __align__(16) u16 sA[2][128*32], sB[2][128*32];
    const int lin = blockIdx.x + (blockIdx.y << 3) + (blockIdx.z << 8); // 0..767
    const int n0 = (lin & 7) * 128;
    const int idx = lin >> 3;            // 0..95 within XCD
    const int z   = idx >> 5;            // weight, panel-serial within XCD
    const int m0  = (idx & 31) * 128;
    const u16* Bh = (z == 0) ? qwh : (z == 1) ? kwh : vwh;
    const float* bias = (z == 0) ? q_b : (z == 1) ? k_b : v_b;
    const int t = threadIdx.x;
    const int lane = t & 63, w = t >> 6;
    const int wm = w >> 1, wn = w & 1;
    const int lr = lane & 15, qd = lane >> 4;
    f32x4 acc[4][4] = {};
    const size_t gA = (size_t)(m0 + (t >> 2)) * E_ + (t & 3) * 8;
    const size_t gB = (size_t)(n0 + (t >> 2)) * E_ + (t & 3) * 8;
    for (int k0 = 0; k0 < E_; k0 += 64) {
        #pragma unroll
        for (int half = 0; half < 2; half++) {
            #pragma unroll
            for (int is = 0; is < 2; is++) {
                const int ldo = (is * 256 + (t & 192)) * 16;
                const size_t ro = (size_t)is * 64 * E_;
                gl2lds16(Ah + gA + ro + k0 + half*32, (char*)sA[half] + ldo);
                gl2lds16(Bh + gB + ro + k0 + half*32, (char*)sB[half] + ldo);
            }
        }
        __syncthreads();
        #pragma unroll
        for (int half = 0; half < 2; half++) {
            bf16x8 af[4], bfr[4];
            #pragma unroll
            for (int i = 0; i < 4; i++) {
                af[i]  = *(const bf16x8*)&sA[half][(wm*64 + i*16 + lr)*32 + qd*8];
                bfr[i] = *(const bf16x8*)&sB[half][(wn*64 + i*16 + lr)*32 + qd*8];
            }
            #pragma unroll
            for (int i = 0; i < 4; i++)
                #pragma unroll
                for (int j = 0; j < 4; j++)
                    acc[i][j] = MFMA16(af[i], bfr[j], acc[i][j]);
        }
        __syncthreads();
    }
    const int head = (n0 + wn * 64) >> 6;
    if (z < 2) {
        u16* Oh = (z == 0) ? Qhb : Khb;
        const float osc = (z == 0) ? QSCALE : 1.0f;
        #pragma unroll
        for (int j = 0; j < 2; j++) {
            const int d1 = j * 16 + lr;
            const float b1 = bias[head * 64 + d1];
            const float b2 = bias[head * 64 + d1 + 32];
            #pragma unroll
            for (int i = 0; i < 4; i++) {
                #pragma unroll
                for (int r = 0; r < 4; r++) {
                    const int tok = m0 + wm*64 + i*16 + qd*4 + r;
                    const int bb = tok >> 11, ss = tok & (S_ - 1);
                    const float2 t2 = tab[ss * 32 + d1];
                    const float q1 = acc[i][j][r]   + b1;
                    const float q2 = acc[i][j+2][r] + b2;
                    const size_t o = (((size_t)bb * H_ + head) * S_ + ss) * 64 + d1;
                    Oh[o]    = f2bf((q1 * t2.x - q2 * t2.y) * osc);
                    Oh[o+32] = f2bf((q2 * t2.x + q1 * t2.y) * osc);
                }
            }
        }
    } else {
        #pragma unroll
        for (int j = 0; j < 4; j++) {
            const int d = j * 16 + lr;
            const float bv = bias[head * 64 + d];
            #pragma unroll
            for (int i = 0; i < 4; i++)
                #pragma unroll
                for (int r = 0; r < 4; r++) {
                    const int tok = m0 + wm*64 + i*16 + qd*4 + r;
                    const int bb = tok >> 11, ss = tok & (S_ - 1);
                    Vtb[(((size_t)bb * H_ + head) * 64 + d) * S_ + ss] = f2bf(acc[i][j][r] + bv);
                }
        }
    }
}

// ---------------------------------------------------------------------------
// Flash attention v7: v4 skeleton + T4 counted-vmcnt SPLIT WAIT.
// Staging issue order K,K,V,V per tile. Two barriers per iter:
//   vmcnt(2)+barrier1  -> own K-cur landed (V-cur may fly); then stage next
//   QK^T + exp2 + pack  (V-cur latency hides under this phase)
//   vmcnt(4)+barrier2  -> own V-cur landed; the 4 prefetch loads for the
//                         next tile stay IN FLIGHT (never drained to 0)
//   PV
// Overwrite safety: stage(cur^1) issued after barrier1, which all waves
// reach only after finishing prev iter's PV reads of buf[cur^1]; sV[cur]
// read only after barrier2 (all waves' V-writes drained). LDS 37.25KB, 4/CU.
// ---------------------------------------------------------------------------
__global__ __launch_bounds__(256,4) void attn_kernel(
    const u16* __restrict__ Q, const u16* __restrict__ K,
    const u16* __restrict__ Vt,
    float* __restrict__ Opart, float* __restrict__ lpart)
{
    __shared__ __align__(16) u16 sK[2][64*64];   // frag-major, double-buffered
    __shared__ __align__(16) u16 sV[2][64*64];   // frag-major, double-buffered
    __shared__ __align__(16) u16 sP[4][672];     // per-wave, strips sequential
    const int t = threadIdx.x, lane = t & 63, w = t >> 6;
    const int lr = lane & 15, qd = lane >> 4;
    const int lin = blockIdx.x + (blockIdx.y << 4) + (blockIdx.z << 8);
    const int wg  = ((lin & 7) << 7) + (lin >> 3);
    const int q0 = (wg & 15) << 7;
    const int h  = (wg >> 4) & 15;
    const int zc = wg >> 8;                 // 0..3
    const int b = zc & 1, sc = zc >> 1;
    const size_t bhS = ((size_t)b * H_ + h) * S_;
    const size_t bhD = ((size_t)b * H_ + h) * 64;
    bf16x8 qf[2][2];
    #pragma unroll
    for (int p = 0; p < 2; p++) {
        const size_t qa = (bhS + q0 + p*64 + w*16 + lr) * 64 + qd * 8;
        qf[p][0] = *(const bf16x8*)&Q[qa];
        qf[p][1] = *(const bf16x8*)&Q[qa + 32];
    }
    bf16x8 vOnes;
    #pragma unroll
    for (int i = 0; i < 8; i++) vOnes[i] = (short)0x3F80;
    f32x4 O[2][4] = {};
    f32x4 Ol[2] = {};

    const int CH0 = w*4 + qd, CH1 = (4 + w)*4 + qd;
    const int sbs0 = CH0 >> 3, doff0 = ((CH0 >> 2) & 1)*32 + (CH0 & 3)*8;
    const int sbs1 = CH1 >> 3, doff1 = ((CH1 >> 2) & 1)*32 + (CH1 & 3)*8;
    auto stageK = [&](int bp, int j0) {
        gl2lds16(&K[(bhS + j0 + sbs0*16 + lr)*64 + doff0], (char*)sK[bp] + w*1024);
        gl2lds16(&K[(bhS + j0 + sbs1*16 + lr)*64 + doff1], (char*)sK[bp] + (4+w)*1024);
    };
    auto stageV = [&](int bp, int j0) {
        gl2lds16(&Vt[(bhD + sbs0*16 + lr)*S_ + j0 + doff0], (char*)sV[bp] + w*1024);
        gl2lds16(&Vt[(bhD + sbs1*16 + lr)*S_ + j0 + doff1], (char*)sV[bp] + (4+w)*1024);
    };

    const int jbeg = sc * 1024;
    stageK(0, jbeg);
    stageV(0, jbeg);
    for (int jt = 0; jt < 16; ++jt) {
        const int cur = jt & 1;
        // barrier1: own K-cur landed (2 newest = V-cur may still fly).
        asm volatile("s_waitcnt vmcnt(2) lgkmcnt(0)" ::: "memory");
        __builtin_amdgcn_sched_barrier(0);
        __builtin_amdgcn_s_barrier();
        __builtin_amdgcn_sched_barrier(0);
        if (jt + 1 < 16) {                       // prefetch next tile: K,K,V,V
            stageK(cur ^ 1, jbeg + (jt + 1) * 64);
            stageV(cur ^ 1, jbeg + (jt + 1) * 64);
        }
        // S^T = K Q^T for both strips (K frags shared): D[key][q]
        f32x4 Sv[2][4];
        __builtin_amdgcn_s_setprio(1);
        #pragma unroll
        for (int sb = 0; sb < 4; sb++) {
            bf16x8 k0 = *(const bf16x8*)&sK[cur][(sb*8 + qd)*128 + lr*8];
            bf16x8 k1 = *(const bf16x8*)&sK[cur][(sb*8 + 4 + qd)*128 + lr*8];
            f32x4 a0 = {}, a1 = {};
            a0 = MFMA16(k0, qf[0][0], a0);
            a0 = MFMA16(k1, qf[0][1], a0);
            a1 = MFMA16(k0, qf[1][0], a1);
            a1 = MFMA16(k1, qf[1][1], a1);
            Sv[0][sb] = a0;
            Sv[1][sb] = a1;
        }
        __builtin_amdgcn_s_setprio(0);
        uint2 pk[2][4];
        #pragma unroll
        for (int p = 0; p < 2; p++) {
            #pragma unroll
            for (int sb = 0; sb < 4; sb++) {
                const float pv0 = EXP2(Sv[p][sb][0]);
                const float pv1 = EXP2(Sv[p][sb][1]);
                const float pv2 = EXP2(Sv[p][sb][2]);
                const float pv3 = EXP2(Sv[p][sb][3]);
                pk[p][sb].x = __builtin_amdgcn_perm(__float_as_uint(pv1),
                                                    __float_as_uint(pv0), 0x07060302u);
                pk[p][sb].y = __builtin_amdgcn_perm(__float_as_uint(pv3),
                                                    __float_as_uint(pv2), 0x07060302u);
            }
        }
        // barrier2: own V-cur landed; the 4 prefetch loads stay in flight.
        asm volatile("s_waitcnt vmcnt(4) lgkmcnt(0)" ::: "memory");
        __builtin_amdgcn_sched_barrier(0);
        __builtin_amdgcn_s_barrier();
        __builtin_amdgcn_sched_barrier(0);
        bf16x8 vv[8];
        #pragma unroll
        for (int ds = 0; ds < 4; ds++) {
            vv[2*ds]   = *(const bf16x8*)&sV[cur][(ds*8 + qd)*128 + lr*8];
            vv[2*ds+1] = *(const bf16x8*)&sV[cur][(ds*8 + 4 + qd)*128 + lr*8];
        }
        #pragma unroll
        for (int p = 0; p < 2; p++) {
            #pragma unroll
            for (int sb = 0; sb < 4; sb++)
                *(uint2*)&sP[w][lr*40 + sb*16 + qd*4] = pk[p][sb];
            bf16x8 p0 = *(const bf16x8*)&sP[w][lr*40 + qd*8];
            bf16x8 p1 = *(const bf16x8*)&sP[w][lr*40 + 32 + qd*8];
            __builtin_amdgcn_s_setprio(1);
            #pragma unroll
            for (int ds = 0; ds < 4; ds++) {
                O[p][ds] = MFMA16(p0, vv[2*ds],   O[p][ds]);
                O[p][ds] = MFMA16(p1, vv[2*ds+1], O[p][ds]);
            }
            Ol[p] = MFMA16(p0, vOnes, Ol[p]);
            Ol[p] = MFMA16(p1, vOnes, Ol[p]);
            __builtin_amdgcn_s_setprio(0);
        }
    }
    float* Op = Opart + (size_t)sc * TOKENS * E_;
    float* lp = lpart + (size_t)sc * TOKENS * H_;
    if (lr == 0) {
        #pragma unroll
        for (int p = 0; p < 2; p++)
            #pragma unroll
            for (int r = 0; r < 4; r++)
                lp[(size_t)(b*S_ + q0 + p*64 + w*16 + qd*4 + r) * H_ + h] = Ol[p][r];
    }
    #pragma unroll
    for (int p = 0; p < 2; p++) {
        const int qb = q0 + p*64 + w*16 + qd*4;
        #pragma unroll
        for (int ds = 0; ds < 4; ds++)
            #pragma unroll
            for (int r = 0; r < 4; r++)
                Op[(size_t)(b*S_ + qb + r) * E_ + h*64 + ds*16 + lr] = O[p][ds][r];
    }
}

// ---------------------------------------------------------------------------
// Combine split-S partials + gate + top2. WAVE-PER-TOKEN (4 tokens/block,
// grid 1024): lane owns 16 contiguous dims, gate reduced with the 27-shfl
// transpose trick, top2 on lane 0. Zero LDS, zero __syncthreads.
// ---------------------------------------------------------------------------
__global__ __launch_bounds__(256) void combine_gate(
    const float* __restrict__ Opart, const float* __restrict__ lpart,
    const float* __restrict__ gate_w, const float* __restrict__ gate_b,
    u16* __restrict__ attn_bf, float* __restrict__ gval, int* __restrict__ eidx)
{
    const int t = threadIdx.x, lane = t & 63, w = t >> 6;
    const int tok = blockIdx.x * 4 + w;
    const int d0 = lane * 16;
    const int h = d0 >> 6;
    const float l = lpart[(size_t)tok*H_ + h] + lpart[(size_t)(TOKENS + tok)*H_ + h];
    const float inv = 1.f / l;
    const float4* p1 = (const float4*)&Opart[(size_t)tok*E_ + d0];
    const float4* p2 = (const float4*)&Opart[(size_t)(TOKENS + tok)*E_ + d0];
    float v[16];
    #pragma unroll
    for (int c = 0; c < 4; c++) {
        const float4 a = p1[c], bb = p2[c];
        v[4*c+0] = (a.x + bb.x) * inv;
        v[4*c+1] = (a.y + bb.y) * inv;
        v[4*c+2] = (a.z + bb.z) * inv;
        v[4*c+3] = (a.w + bb.w) * inv;
    }
    u32 hw[8];
    #pragma unroll
    for (int i = 0; i < 8; i++)
        hw[i] = ((u32)f2bf(v[2*i+1]) << 16) | f2bf(v[2*i]);
    uint4* dst = (uint4*)&attn_bf[(size_t)tok*E_ + d0];
    dst[0] = make_uint4(hw[0], hw[1], hw[2], hw[3]);
    dst[1] = make_uint4(hw[4], hw[5], hw[6], hw[7]);
    float pe[NE_];
    #pragma unroll
    for (int e = 0; e < NE_; e++) {
        const float4* g = (const float4*)&gate_w[e*E_ + d0];
        float s = 0.f;
        #pragma unroll
        for (int c = 0; c < 4; c++) {
            const float4 gc = g[c];
            s += v[4*c]*gc.x + v[4*c+1]*gc.y + v[4*c+2]*gc.z + v[4*c+3]*gc.w;
        }
        pe[e] = s;
    }
    #pragma unroll
    for (int e = 0; e < NE_; e++) {
        pe[e] += __shfl_xor(pe[e], 32, 64);
        pe[e] += __shfl_xor(pe[e], 16, 64);
        pe[e] += __shfl_xor(pe[e], 8, 64);
    }
    const int ei = lane >> 3;
    float x = pe[0];
    #pragma unroll
    for (int e = 1; e < NE_; e++) x = (ei == e) ? pe[e] : x;
    x += __shfl_xor(x, 4, 64);
    x += __shfl_xor(x, 2, 64);
    x += __shfl_xor(x, 1, 64);
    float lg[NE_];
    #pragma unroll
    for (int e = 0; e < NE_; e++) lg[e] = __shfl(x, e << 3, 64) + gate_b[e];
    if (lane == 0) {
        float m = lg[0];
        #pragma unroll
        for (int e = 1; e < NE_; e++) m = fmaxf(m, lg[e]);
        float ex[NE_], ssum = 0.f;
        #pragma unroll
        for (int e = 0; e < NE_; e++) { ex[e] = __expf(lg[e]-m); ssum += ex[e]; }
        const float invs = 1.f / ssum;
        int i0 = 0;
        #pragma unroll
        for (int e = 1; e < NE_; e++) if (lg[e] > lg[i0]) i0 = e;
        int i1 = (i0 == 0) ? 1 : 0;
        #pragma unroll
        for (int e = 0; e < NE_; e++) if (e != i0 && lg[e] > lg[i1]) i1 = e;
        eidx[tok*2]     = i0;
        gval[tok*2]     = ex[i0]*invs;
        eidx[tok*2 + 1] = i1;
        gval[tok*2 + 1] = ex[i1]*invs;
    }
}

// ---------------------------------------------------------------------------
// Build per-expert token lists: LDS histogram per block (512 entries),
// then 8 global atomics per block to reserve ranges, then scatter.
// ---------------------------------------------------------------------------
__global__ __launch_bounds__(256) void build_lists_kernel(
    const int* __restrict__ eidx, int* __restrict__ list, int* __restrict__ counts)
{
    __shared__ int lcnt[NE_], lbase[NE_];
    const int t = threadIdx.x;
    if (t < NE_) lcnt[t] = 0;
    __syncthreads();
    const int ent = blockIdx.x * 512 + t * 2;
    const int e0 = eidx[ent], e1 = eidx[ent + 1];
    const int p0 = atomicAdd(&lcnt[e0], 1);
    const int p1 = atomicAdd(&lcnt[e1], 1);
    __syncthreads();
    if (t < NE_) lbase[t] = atomicAdd(&counts[t], lcnt[t]);
    __syncthreads();
    list[e0 * TOKENS + lbase[e0] + p0] = ent;
    list[e1 * TOKENS + lbase[e1] + p1] = ent + 1;
}

// ---------------------------------------------------------------------------
// Gathered expert GEMM (bf16): sel[ent] = g * (attn[tok] @ ew[e]^T + eb[e])
// BK=64 paired half-tiles. XCD swizzle: xcd = n0-column.
// ---------------------------------------------------------------------------
__global__ __launch_bounds__(256,3) void gemm_expert(
    const u16* __restrict__ Abf, const u16* __restrict__ ewh,
    const float* __restrict__ eb, const int* __restrict__ list,
    const int* __restrict__ counts, const float* __restrict__ gval,
    u16* __restrict__ sel)
{
    const int lin = blockIdx.x + (blockIdx.y << 3) + (blockIdx.z << 8); // 0..2047
    const int n0 = (lin & 7) * 128;
    const int idx = lin >> 3;            // 0..255 within XCD
    const int e   = idx >> 5;            // expert, panel-serial within XCD
    const int m0  = (idx & 31) * 128;
    const int cnt = counts[e];
    if (m0 >= cnt) return;
    __shared__ __align__(16) u16 sA[2][128*32], sB[2][128*32];
    __shared__ int sEnt[128];
    const int t = threadIdx.x;
    if (t < 128) sEnt[t] = (m0 + t < cnt) ? list[e * TOKENS + m0 + t] : -1;
    __syncthreads();
    const int lane = t & 63, w = t >> 6;
    const int wm = w >> 1, wn = w & 1;
    const int lr = lane & 15, qd = lane >> 4;
    const int e0 = sEnt[t >> 2], e1 = sEnt[64 + (t >> 2)];
    const u16* ga0 = Abf + (size_t)(e0 < 0 ? 0 : (e0 >> 1)) * E_ + (t & 3) * 8;
    const u16* ga1 = Abf + (size_t)(e1 < 0 ? 0 : (e1 >> 1)) * E_ + (t & 3) * 8;
    const u16* gb0 = ewh + (size_t)e * E_ * E_ + (size_t)(n0 + (t >> 2)) * E_ + (t & 3) * 8;
    const u16* gb1 = gb0 + 64 * E_;
    f32x4 acc[4][4] = {};
    for (int k0 = 0; k0 < E_; k0 += 64) {
        #pragma unroll
        for (int half = 0; half < 2; half++) {
            const int l0 = (t & 192) * 16;
            const int l1 = (256 + (t & 192)) * 16;
            const int kk = k0 + half*32;
            gl2lds16(ga0 + kk, (char*)sA[half] + l0);
            gl2lds16(ga1 + kk, (char*)sA[half] + l1);
            gl2lds16(gb0 + kk, (char*)sB[half] + l0);
            gl2lds16(gb1 + kk, (char*)sB[half] + l1);
        }
        __syncthreads();
        #pragma unroll
        for (int half = 0; half < 2; half++) {
            bf16x8 af[4], bfr[4];
            #pragma unroll
            for (int i = 0; i < 4; i++) {
                af[i]  = *(const bf16x8*)&sA[half][(wm*64 + i*16 + lr)*32 + qd*8];
                bfr[i] = *(const bf16x8*)&sB[half][(wn*64 + i*16 + lr)*32 + qd*8];
            }
            #pragma unroll
            for (int i = 0; i < 4; i++)
                #pragma unroll
                for (int j = 0; j < 4; j++)
                    acc[i][j] = MFMA16(af[i], bfr[j], acc[i][j]);
        }
        __syncthreads();
    }
    #pragma unroll
    for (int i = 0; i < 4; i++)
        #pragma unroll
        for (int r = 0; r < 4; r++) {
            const int local = wm*64 + i*16 + qd*4 + r;
            const int ent = sEnt[local];
            if (ent < 0) continue;
            const float g = gval[ent];
            #pragma unroll
            for (int j = 0; j < 4; j++) {
                const int col = n0 + wn*64 + j*16 + lr;
                sel[(size_t)ent * E_ + col] = f2bf((acc[i][j][r] + eb[e * E_ + col]) * g);
            }
        }
}

// ---------------------------------------------------------------------------
// moe[tok] = sel[tok*2] + sel[tok*2+1]  (bf16 in/out)
// ---------------------------------------------------------------------------
__global__ void combine_kernel(const u16* __restrict__ sel, u16* __restrict__ moe)
{
    const int g = blockIdx.x * 256 + threadIdx.x;
    const int tok = g >> 8;
    const int c = (g & 255) * 4;
    const u16* a = sel + (size_t)tok * 2048 + c;
    float o[4];
    #pragma unroll
    for (int j = 0; j < 4; j++) o[j] = bf2f(a[j]) + bf2f(a[1024 + j]);
    ushort4 R = {f2bf(o[0]), f2bf(o[1]), f2bf(o[2]), f2bf(o[3])};
    *(ushort4*)(moe + (size_t)tok * E_ + c) = R;
}

// ---------------------------------------------------------------------------
// FFN GEMM (bf16) + bias + fp32 residual -> fp32 out.
// 128x64 tiles -> 512 blocks @3/CU (full device). BK=64 paired half tiles;
// XCD swizzle: each XCD owns n-tiles {x, x+8}.
// ---------------------------------------------------------------------------
__global__ __launch_bounds__(256,3) void gemm_ffn(
    const u16* __restrict__ Ah, const u16* __restrict__ Bh,
    const float* __restrict__ bias, const float* __restrict__ res,
    float* __restrict__ C)
{
    __shared__ __align__(16) u16 sA[2][128*32], sB[2][64*32];
    const int t = threadIdx.x;
    const int lin = blockIdx.x + (blockIdx.y << 4);   // 0..511
    const int idx = lin >> 3;                          // 0..63 within XCD
    const int m0 = (idx & 31) * 128;
    const int n0 = ((idx >> 5) * 8 + (lin & 7)) * 64;  // n-tile 0..15
    const int lane = t & 63, w = t >> 6;
    const int wm = w >> 1, wn = w & 1;
    const int lr = lane & 15, qd = lane >> 4;
    f32x4 acc[4][2] = {};
    const size_t gA = (size_t)(m0 + (t >> 2)) * E_ + (t & 3) * 8;
    const size_t gB = (size_t)(n0 + (t >> 2)) * E_ + (t & 3) * 8;
    for (int k0 = 0; k0 < E_; k0 += 64) {
        #pragma unroll
        for (int half = 0; half < 2; half++) {
            const int kk = k0 + half*32;
            #pragma unroll
            for (int is = 0; is < 2; is++) {
                const int ldo = (is * 256 + (t & 192)) * 16;
                const size_t ro = (size_t)is * 64 * E_;
                gl2lds16(Ah + gA + ro + kk, (char*)sA[half] + ldo);
            }
            gl2lds16(Bh + gB + kk, (char*)sB[half] + t*16);   // 64 rows x 32 cols
        }
        __syncthreads();
        #pragma unroll
        for (int half = 0; half < 2; half++) {
            bf16x8 af[4], bfr[2];
            #pragma unroll
            for (int i = 0; i < 4; i++)
                af[i] = *(const bf16x8*)&sA[half][(wm*64 + i*16 + lr)*32 + qd*8];
            #pragma unroll
            for (int j = 0; j < 2; j++)
                bfr[j] = *(const bf16x8*)&sB[half][(wn*32 + j*16 + lr)*32 + qd*8];
            #pragma unroll
            for (int i = 0; i < 4; i++)
                #pragma unroll
                for (int j = 0; j < 2; j++)
                    acc[i][j] = MFMA16(af[i], bfr[j], acc[i][j]);
        }
        __syncthreads();
    }
    #pragma unroll
    for (int i = 0; i < 4; i++)
        #pragma unroll
        for (int r = 0; r < 4; r++) {
            const int tok = m0 + wm*64 + i*16 + qd*4 + r;
            #pragma unroll
            for (int j = 0; j < 2; j++) {
                const int col = n0 + wn*32 + j*16 + lr;
                C[(size_t)tok * E_ + col] = acc[i][j][r] + bias[col] + res[(size_t)tok * E_ + col];
            }
        }
}

// ---------------------------------------------------------------------------
extern "C" void kernel_launch(void* const* d_in, const int* in_sizes, int n_in,
                              void* d_out, int out_size, void* d_ws, size_t ws_size,
                              hipStream_t stream) {
    const float* x      = (const float*)d_in[0];
    const float* q_w    = (const float*)d_in[1];
    const float* q_b    = (const float*)d_in[2];
    const float* k_w    = (const float*)d_in[3];
    const float* k_b    = (const float*)d_in[4];
    const float* v_w    = (const float*)d_in[5];
    const float* v_b    = (const float*)d_in[6];
    const float* gate_w = (const float*)d_in[7];
    const float* gate_b = (const float*)d_in[8];
    const float* ew     = (const float*)d_in[9];
    const float* eb     = (const float*)d_in[10];
    const float* ffn_w  = (const float*)d_in[11];
    const float* ffn_b  = (const float*)d_in[12];
    float* out = (float*)d_out;

    char* p = (char*)d_ws;
    auto alloc = [&](size_t bytes) { char* r = p; p += (bytes + 255) & ~(size_t)255; return r; };
    u16* xh   = (u16*)alloc((size_t)TOKENS*E_*2);
    u16* qwh  = (u16*)alloc((size_t)E_*E_*2);
    u16* kwh  = (u16*)alloc((size_t)E_*E_*2);
    u16* vwh  = (u16*)alloc((size_t)E_*E_*2);
    u16* fwh  = (u16*)alloc((size_t)E_*E_*2);
    u16* ewh  = (u16*)alloc((size_t)NE_*E_*E_*2);
    u16* Qhb  = (u16*)alloc((size_t)TOKENS*E_*2);
    u16* Khb  = (u16*)alloc((size_t)TOKENS*E_*2);
    u16* Vtb  = (u16*)alloc((size_t)TOKENS*E_*2);
    u16* abf  = (u16*)alloc((size_t)TOKENS*E_*2);
    float* Opart = (float*)alloc((size_t)2*TOKENS*E_*4);
    float* lpart = (float*)alloc((size_t)2*TOKENS*H_*4);
    u16* selb = (u16*)alloc((size_t)2*TOKENS*E_*2);
    u16* moeb = (u16*)alloc((size_t)TOKENS*E_*2);
    float2* rtab = (float2*)alloc((size_t)S_*32*8);
    float* gvl = (float*)alloc((size_t)2*TOKENS*4);
    int*   eix = (int*)alloc((size_t)2*TOKENS*4);
    int*   lst = (int*)alloc((size_t)NE_*TOKENS*4);
    int*   cnt = (int*)alloc(256);

    hipMemsetAsync(cnt, 0, 256, stream);

    cvt_all_k<<<16640, 256, 0, stream>>>(x, q_w, k_w, v_w, ffn_w, ew,
                                         xh, qwh, kwh, vwh, fwh, ewh, rtab);

    gemm_qkv<<<dim3(8,32,3), 256, 0, stream>>>(xh, qwh, kwh, vwh,
                                               q_b, k_b, v_b, rtab,
                                               Qhb, Khb, Vtb);

    attn_kernel<<<dim3(16,16,4), 256, 0, stream>>>(Qhb, Khb, Vtb, Opart, lpart);

    combine_gate<<<TOKENS/4, 256, 0, stream>>>(Opart, lpart, gate_w, gate_b,
                                               abf, gvl, eix);
    build_lists_kernel<<<TOKENS/256, 256, 0, stream>>>(eix, lst, cnt);
    gemm_expert<<<dim3(8,32,8), 256, 0, stream>>>(abf, ewh, eb, lst, cnt, gvl, selb);
    combine_kernel<<<4096, 256, 0, stream>>>(selb, moeb);
    gemm_ffn<<<dim3(16,32), 256, 0, stream>>>(moeb, fwh, ffn_b, x, out);
}

// Round 12
// 289.459 us; speedup vs baseline: 1.0183x; 1.0183x over previous
//
#include <hip/hip_runtime.h>
#include <hip/hip_bf16.h>

#define B_ 2
#define S_ 2048
#define E_ 1024
#define H_ 16
#define D_ 64
#define NE_ 8
#define TOKENS (B_*S_)   // 4096
#define QSCALE 0.18033688011112043f   // log2(e)/8, folded into Q

typedef __attribute__((ext_vector_type(8))) short bf16x8;
typedef __attribute__((ext_vector_type(4))) float f32x4;
typedef unsigned short u16;
typedef unsigned int u32;

#if __has_builtin(__builtin_amdgcn_exp2f)
#define EXP2(x) __builtin_amdgcn_exp2f(x)
#else
#define EXP2(x) exp2f(x)
#endif

__device__ __forceinline__ u16 f2bf(float f) {
    u32 u = __float_as_uint(f);
    u32 r = u + 0x7fffu + ((u >> 16) & 1u);
    return (u16)(r >> 16);
}
__device__ __forceinline__ float bf2f(u16 h) {
    return __uint_as_float(((u32)h) << 16);
}
__device__ __forceinline__ float bflo(u32 wd) {
    return __uint_as_float(wd << 16);
}
__device__ __forceinline__ float bfhi(u32 wd) {
    return __uint_as_float(wd & 0xffff0000u);
}
__device__ __forceinline__ void gl2lds16(const void* g, void* l) {
    __builtin_amdgcn_global_load_lds(
        (__attribute__((address_space(1))) void*)(g),
        (__attribute__((address_space(3))) void*)(l), 16, 0, 0);
}
#define MFMA16(a,b,c) __builtin_amdgcn_mfma_f32_16x16x32_bf16(a,b,c,0,0,0)

// ---------------------------------------------------------------------------
// Fused fp32 -> bf16 conversion for all six tensors + RoPE table (one dispatch).
// Blocks 0..255: cos/sin table FIRST (sincos-heavy; overlaps the streaming
// blocks instead of straggling the tail). Blocks 256..16639: conversions.
// ---------------------------------------------------------------------------
__global__ void cvt_all_k(
    const float* __restrict__ x,  const float* __restrict__ qw,
    const float* __restrict__ kw, const float* __restrict__ vw,
    const float* __restrict__ fw, const float* __restrict__ ew,
    u16* __restrict__ xh,  u16* __restrict__ qwh, u16* __restrict__ kwh,
    u16* __restrict__ vwh, u16* __restrict__ fwh, u16* __restrict__ ewh,
    float2* __restrict__ tab)
{
    const int blk = blockIdx.x;
    if (blk < 256) {
        const int idx = blk * 256 + threadIdx.x;   // < 65536
        const int s = idx >> 5, d1 = idx & 31;
        const float inv = exp2f(-(float)d1 * 0.41524101186091903f);
        float sn, cs;
        sincosf((float)s * inv, &sn, &cs);
        tab[idx] = make_float2(cs, sn);
        return;
    }
    const int b2 = blk - 256;
    const float* s; u16* d; int off;
    if (b2 < 4096)      { s = x;  d = xh;  off = b2; }
    else if (b2 < 5120) { s = qw; d = qwh; off = b2 - 4096; }
    else if (b2 < 6144) { s = kw; d = kwh; off = b2 - 5120; }
    else if (b2 < 7168) { s = vw; d = vwh; off = b2 - 6144; }
    else if (b2 < 8192) { s = fw; d = fwh; off = b2 - 7168; }
    else                { s = ew; d = ewh; off = b2 - 8192; }
    const size_t i = (size_t)off * 256 + threadIdx.x;
    const float4 v = *(const float4*)(s + i * 4);
    ushort4 H = {f2bf(v.x), f2bf(v.y), f2bf(v.z), f2bf(v.w)};
    *(ushort4*)(d + i * 4) = H;
}

// ---------------------------------------------------------------------------
// Fused Q/K/V projection GEMM. 128x128 tile, BK=64 as two [128][32] half
// tiles. XCD swizzle: lin%8 = n0-column. 768 blocks @3/CU: full device.
// z<2: RoPE epilogue, head-major [b][h][s][d] bf16 (Q scaled by QSCALE).
// z=2: transposed store Vt[b][h][d][s].
// ---------------------------------------------------------------------------
__global__ __launch_bounds__(256,3) void gemm_qkv(
    const u16* __restrict__ Ah,
    const u16* __restrict__ qwh, const u16* __restrict__ kwh,
    const u16* __restrict__ vwh,
    const float* __restrict__ q_b, const float* __restrict__ k_b,
    const float* __restrict__ v_b,
    const float2* __restrict__ tab,
    u16* __restrict__ Qhb, u16* __restrict__ Khb, u16* __restrict__ Vtb)
{
    __shared__ __align__(16) u16 sA[2][128*32], sB[2][128*32];
    const int lin = blockIdx.x + (blockIdx.y << 3) + (blockIdx.z << 8); // 0..767
    const int n0 = (lin & 7) * 128;
    const int idx = lin >> 3;            // 0..95 within XCD
    const int z   = idx >> 5;            // weight, panel-serial within XCD
    const int m0  = (idx & 31) * 128;
    const u16* Bh = (z == 0) ? qwh : (z == 1) ? kwh : vwh;
    const float* bias = (z == 0) ? q_b : (z == 1) ? k_b : v_b;
    const int t = threadIdx.x;
    const int lane = t & 63, w = t >> 6;
    const int wm = w >> 1, wn = w & 1;
    const int lr = lane & 15, qd = lane >> 4;
    f32x4 acc[4][4] = {};
    const size_t gA = (size_t)(m0 + (t >> 2)) * E_ + (t & 3) * 8;
    const size_t gB = (size_t)(n0 + (t >> 2)) * E_ + (t & 3) * 8;
    for (int k0 = 0; k0 < E_; k0 += 64) {
        #pragma unroll
        for (int half = 0; half < 2; half++) {
            #pragma unroll
            for (int is = 0; is < 2; is++) {
                const int ldo = (is * 256 + (t & 192)) * 16;
                const size_t ro = (size_t)is * 64 * E_;
                gl2lds16(Ah + gA + ro + k0 + half*32, (char*)sA[half] + ldo);
                gl2lds16(Bh + gB + ro + k0 + half*32, (char*)sB[half] + ldo);
            }
        }
        __syncthreads();
        #pragma unroll
        for (int half = 0; half < 2; half++) {
            bf16x8 af[4], bfr[4];
            #pragma unroll
            for (int i = 0; i < 4; i++) {
                af[i]  = *(const bf16x8*)&sA[half][(wm*64 + i*16 + lr)*32 + qd*8];
                bfr[i] = *(const bf16x8*)&sB[half][(wn*64 + i*16 + lr)*32 + qd*8];
            }
            #pragma unroll
            for (int i = 0; i < 4; i++)
                #pragma unroll
                for (int j = 0; j < 4; j++)
                    acc[i][j] = MFMA16(af[i], bfr[j], acc[i][j]);
        }
        __syncthreads();
    }
    const int head = (n0 + wn * 64) >> 6;
    if (z < 2) {
        u16* Oh = (z == 0) ? Qhb : Khb;
        const float osc = (z == 0) ? QSCALE : 1.0f;
        #pragma unroll
        for (int j = 0; j < 2; j++) {
            const int d1 = j * 16 + lr;
            const float b1 = bias[head * 64 + d1];
            const float b2 = bias[head * 64 + d1 + 32];
            #pragma unroll
            for (int i = 0; i < 4; i++) {
                #pragma unroll
                for (int r = 0; r < 4; r++) {
                    const int tok = m0 + wm*64 + i*16 + qd*4 + r;
                    const int bb = tok >> 11, ss = tok & (S_ - 1);
                    const float2 t2 = tab[ss * 32 + d1];
                    const float q1 = acc[i][j][r]   + b1;
                    const float q2 = acc[i][j+2][r] + b2;
                    const size_t o = (((size_t)bb * H_ + head) * S_ + ss) * 64 + d1;
                    Oh[o]    = f2bf((q1 * t2.x - q2 * t2.y) * osc);
                    Oh[o+32] = f2bf((q2 * t2.x + q1 * t2.y) * osc);
                }
            }
        }
    } else {
        #pragma unroll
        for (int j = 0; j < 4; j++) {
            const int d = j * 16 + lr;
            const float bv = bias[head * 64 + d];
            #pragma unroll
            for (int i = 0; i < 4; i++)
                #pragma unroll
                for (int r = 0; r < 4; r++) {
                    const int tok = m0 + wm*64 + i*16 + qd*4 + r;
                    const int bb = tok >> 11, ss = tok & (S_ - 1);
                    Vtb[(((size_t)bb * H_ + head) * 64 + d) * S_ + ss] = f2bf(acc[i][j][r] + bv);
                }
        }
    }
}

// ---------------------------------------------------------------------------
// Flash attention v4 (verified 50.2-52.7us, single-barrier counted pipeline):
// 128 q-rows/block (2 strips per wave), split-S x2 -> 1024 blocks = 4/CU,
// double-buffered K/V, ONE raw s_barrier per tile with prefetch in flight
// across compute, XCD-aware swizzle, strips share one per-wave sP buffer.
// NEW: partials stored BF16 (halves the 67MB Opart round-trip; lsum fp32).
// ---------------------------------------------------------------------------
__global__ __launch_bounds__(256,4) void attn_kernel(
    const u16* __restrict__ Q, const u16* __restrict__ K,
    const u16* __restrict__ Vt,
    u16* __restrict__ Opart, float* __restrict__ lpart)
{
    __shared__ __align__(16) u16 sK[2][64*64];   // frag-major, double-buffered
    __shared__ __align__(16) u16 sV[2][64*64];   // frag-major, double-buffered
    __shared__ __align__(16) u16 sP[4][672];     // per-wave, strips sequential
    const int t = threadIdx.x, lane = t & 63, w = t >> 6;
    const int lr = lane & 15, qd = lane >> 4;
    const int lin = blockIdx.x + (blockIdx.y << 4) + (blockIdx.z << 8);
    const int wg  = ((lin & 7) << 7) + (lin >> 3);
    const int q0 = (wg & 15) << 7;
    const int h  = (wg >> 4) & 15;
    const int zc = wg >> 8;                 // 0..3
    const int b = zc & 1, sc = zc >> 1;
    const size_t bhS = ((size_t)b * H_ + h) * S_;
    const size_t bhD = ((size_t)b * H_ + h) * 64;
    bf16x8 qf[2][2];
    #pragma unroll
    for (int p = 0; p < 2; p++) {
        const size_t qa = (bhS + q0 + p*64 + w*16 + lr) * 64 + qd * 8;
        qf[p][0] = *(const bf16x8*)&Q[qa];
        qf[p][1] = *(const bf16x8*)&Q[qa + 32];
    }
    bf16x8 vOnes;
    #pragma unroll
    for (int i = 0; i < 8; i++) vOnes[i] = (short)0x3F80;
    f32x4 O[2][4] = {};
    f32x4 Ol[2] = {};

    const int CH0 = w*4 + qd, CH1 = (4 + w)*4 + qd;
    const int sbs0 = CH0 >> 3, doff0 = ((CH0 >> 2) & 1)*32 + (CH0 & 3)*8;
    const int sbs1 = CH1 >> 3, doff1 = ((CH1 >> 2) & 1)*32 + (CH1 & 3)*8;
    auto stage = [&](int bp, int j0) {
        gl2lds16(&K [(bhS + j0 + sbs0*16 + lr)*64 + doff0], (char*)sK[bp] + w*1024);
        gl2lds16(&Vt[(bhD + sbs0*16 + lr)*S_ + j0 + doff0], (char*)sV[bp] + w*1024);
        gl2lds16(&K [(bhS + j0 + sbs1*16 + lr)*64 + doff1], (char*)sK[bp] + (4+w)*1024);
        gl2lds16(&Vt[(bhD + sbs1*16 + lr)*S_ + j0 + doff1], (char*)sV[bp] + (4+w)*1024);
    };

    const int jbeg = sc * 1024;
    stage(0, jbeg);
    for (int jt = 0; jt < 16; ++jt) {
        const int cur = jt & 1;
        asm volatile("s_waitcnt vmcnt(0) lgkmcnt(0)" ::: "memory");
        __builtin_amdgcn_sched_barrier(0);
        __builtin_amdgcn_s_barrier();
        __builtin_amdgcn_sched_barrier(0);
        if (jt + 1 < 16) stage(cur ^ 1, jbeg + (jt + 1) * 64);  // in flight across compute
        // S^T = K Q^T for both strips (K frags shared): D[key][q]
        f32x4 Sv[2][4];
        __builtin_amdgcn_s_setprio(1);
        #pragma unroll
        for (int sb = 0; sb < 4; sb++) {
            bf16x8 k0 = *(const bf16x8*)&sK[cur][(sb*8 + qd)*128 + lr*8];
            bf16x8 k1 = *(const bf16x8*)&sK[cur][(sb*8 + 4 + qd)*128 + lr*8];
            f32x4 a0 = {}, a1 = {};
            a0 = MFMA16(k0, qf[0][0], a0);
            a0 = MFMA16(k1, qf[0][1], a0);
            a1 = MFMA16(k0, qf[1][0], a1);
            a1 = MFMA16(k1, qf[1][1], a1);
            Sv[0][sb] = a0;
            Sv[1][sb] = a1;
        }
        __builtin_amdgcn_s_setprio(0);
        uint2 pk[2][4];
        #pragma unroll
        for (int p = 0; p < 2; p++) {
            #pragma unroll
            for (int sb = 0; sb < 4; sb++) {
                const float pv0 = EXP2(Sv[p][sb][0]);
                const float pv1 = EXP2(Sv[p][sb][1]);
                const float pv2 = EXP2(Sv[p][sb][2]);
                const float pv3 = EXP2(Sv[p][sb][3]);
                pk[p][sb].x = __builtin_amdgcn_perm(__float_as_uint(pv1),
                                                    __float_as_uint(pv0), 0x07060302u);
                pk[p][sb].y = __builtin_amdgcn_perm(__float_as_uint(pv3),
                                                    __float_as_uint(pv2), 0x07060302u);
            }
        }
        bf16x8 vv[8];
        #pragma unroll
        for (int ds = 0; ds < 4; ds++) {
            vv[2*ds]   = *(const bf16x8*)&sV[cur][(ds*8 + qd)*128 + lr*8];
            vv[2*ds+1] = *(const bf16x8*)&sV[cur][(ds*8 + 4 + qd)*128 + lr*8];
        }
        #pragma unroll
        for (int p = 0; p < 2; p++) {
            #pragma unroll
            for (int sb = 0; sb < 4; sb++)
                *(uint2*)&sP[w][lr*40 + sb*16 + qd*4] = pk[p][sb];
            bf16x8 p0 = *(const bf16x8*)&sP[w][lr*40 + qd*8];
            bf16x8 p1 = *(const bf16x8*)&sP[w][lr*40 + 32 + qd*8];
            __builtin_amdgcn_s_setprio(1);
            #pragma unroll
            for (int ds = 0; ds < 4; ds++) {
                O[p][ds] = MFMA16(p0, vv[2*ds],   O[p][ds]);
                O[p][ds] = MFMA16(p1, vv[2*ds+1], O[p][ds]);
            }
            Ol[p] = MFMA16(p0, vOnes, Ol[p]);
            Ol[p] = MFMA16(p1, vOnes, Ol[p]);
            __builtin_amdgcn_s_setprio(0);
        }
    }
    u16* Op = Opart + (size_t)sc * TOKENS * E_;
    float* lp = lpart + (size_t)sc * TOKENS * H_;
    if (lr == 0) {
        #pragma unroll
        for (int p = 0; p < 2; p++)
            #pragma unroll
            for (int r = 0; r < 4; r++)
                lp[(size_t)(b*S_ + q0 + p*64 + w*16 + qd*4 + r) * H_ + h] = Ol[p][r];
    }
    #pragma unroll
    for (int p = 0; p < 2; p++) {
        const int qb = q0 + p*64 + w*16 + qd*4;
        #pragma unroll
        for (int ds = 0; ds < 4; ds++)
            #pragma unroll
            for (int r = 0; r < 4; r++)
                Op[(size_t)(b*S_ + qb + r) * E_ + h*64 + ds*16 + lr] = f2bf(O[p][ds][r]);
    }
}

// ---------------------------------------------------------------------------
// Combine split-S bf16 partials + gate + top2. WAVE-PER-TOKEN (4 tokens/
// block): lane owns 16 contiguous dims (2x16B bf16 loads per split), gate
// reduced with the 27-shfl transpose trick, top2 on lane 0. No LDS/syncs.
// ---------------------------------------------------------------------------
__global__ __launch_bounds__(256) void combine_gate(
    const u16* __restrict__ Opart, const float* __restrict__ lpart,
    const float* __restrict__ gate_w, const float* __restrict__ gate_b,
    u16* __restrict__ attn_bf, float* __restrict__ gval, int* __restrict__ eidx)
{
    const int t = threadIdx.x, lane = t & 63, w = t >> 6;
    const int tok = blockIdx.x * 4 + w;
    const int d0 = lane * 16;
    const int h = d0 >> 6;
    const float l = lpart[(size_t)tok*H_ + h] + lpart[(size_t)(TOKENS + tok)*H_ + h];
    const float inv = 1.f / l;
    const uint4* p1 = (const uint4*)&Opart[(size_t)tok*E_ + d0];
    const uint4* p2 = (const uint4*)&Opart[(size_t)TOKENS*E_ + (size_t)tok*E_ + d0];
    const uint4 a0 = p1[0], a1 = p1[1];
    const uint4 b0 = p2[0], b1 = p2[1];
    float v[16];
    {
        const u32 aw[8] = {a0.x,a0.y,a0.z,a0.w, a1.x,a1.y,a1.z,a1.w};
        const u32 bw[8] = {b0.x,b0.y,b0.z,b0.w, b1.x,b1.y,b1.z,b1.w};
        #pragma unroll
        for (int i = 0; i < 8; i++) {
            v[2*i]   = (bflo(aw[i]) + bflo(bw[i])) * inv;
            v[2*i+1] = (bfhi(aw[i]) + bfhi(bw[i])) * inv;
        }
    }
    u32 hw[8];
    #pragma unroll
    for (int i = 0; i < 8; i++)
        hw[i] = ((u32)f2bf(v[2*i+1]) << 16) | f2bf(v[2*i]);
    uint4* dst = (uint4*)&attn_bf[(size_t)tok*E_ + d0];
    dst[0] = make_uint4(hw[0], hw[1], hw[2], hw[3]);
    dst[1] = make_uint4(hw[4], hw[5], hw[6], hw[7]);
    float pe[NE_];
    #pragma unroll
    for (int e = 0; e < NE_; e++) {
        const float4* g = (const float4*)&gate_w[e*E_ + d0];
        float s = 0.f;
        #pragma unroll
        for (int c = 0; c < 4; c++) {
            const float4 gc = g[c];
            s += v[4*c]*gc.x + v[4*c+1]*gc.y + v[4*c+2]*gc.z + v[4*c+3]*gc.w;
        }
        pe[e] = s;
    }
    #pragma unroll
    for (int e = 0; e < NE_; e++) {
        pe[e] += __shfl_xor(pe[e], 32, 64);
        pe[e] += __shfl_xor(pe[e], 16, 64);
        pe[e] += __shfl_xor(pe[e], 8, 64);
    }
    const int ei = lane >> 3;
    float x = pe[0];
    #pragma unroll
    for (int e = 1; e < NE_; e++) x = (ei == e) ? pe[e] : x;
    x += __shfl_xor(x, 4, 64);
    x += __shfl_xor(x, 2, 64);
    x += __shfl_xor(x, 1, 64);
    float lg[NE_];
    #pragma unroll
    for (int e = 0; e < NE_; e++) lg[e] = __shfl(x, e << 3, 64) + gate_b[e];
    if (lane == 0) {
        float m = lg[0];
        #pragma unroll
        for (int e = 1; e < NE_; e++) m = fmaxf(m, lg[e]);
        float ex[NE_], ssum = 0.f;
        #pragma unroll
        for (int e = 0; e < NE_; e++) { ex[e] = __expf(lg[e]-m); ssum += ex[e]; }
        const float invs = 1.f / ssum;
        int i0 = 0;
        #pragma unroll
        for (int e = 1; e < NE_; e++) if (lg[e] > lg[i0]) i0 = e;
        int i1 = (i0 == 0) ? 1 : 0;
        #pragma unroll
        for (int e = 0; e < NE_; e++) if (e != i0 && lg[e] > lg[i1]) i1 = e;
        eidx[tok*2]     = i0;
        gval[tok*2]     = ex[i0]*invs;
        eidx[tok*2 + 1] = i1;
        gval[tok*2 + 1] = ex[i1]*invs;
    }
}

// ---------------------------------------------------------------------------
// Build per-expert token lists: LDS histogram per block (512 entries),
// then 8 global atomics per block to reserve ranges, then scatter.
// ---------------------------------------------------------------------------
__global__ __launch_bounds__(256) void build_lists_kernel(
    const int* __restrict__ eidx, int* __restrict__ list, int* __restrict__ counts)
{
    __shared__ int lcnt[NE_], lbase[NE_];
    const int t = threadIdx.x;
    if (t < NE_) lcnt[t] = 0;
    __syncthreads();
    const int ent = blockIdx.x * 512 + t * 2;
    const int e0 = eidx[ent], e1 = eidx[ent + 1];
    const int p0 = atomicAdd(&lcnt[e0], 1);
    const int p1 = atomicAdd(&lcnt[e1], 1);
    __syncthreads();
    if (t < NE_) lbase[t] = atomicAdd(&counts[t], lcnt[t]);
    __syncthreads();
    list[e0 * TOKENS + lbase[e0] + p0] = ent;
    list[e1 * TOKENS + lbase[e1] + p1] = ent + 1;
}

// ---------------------------------------------------------------------------
// Gathered expert GEMM (bf16): sel[ent] = g * (attn[tok] @ ew[e]^T + eb[e])
// BK=64 paired half-tiles. XCD swizzle: xcd = n0-column.
// ---------------------------------------------------------------------------
__global__ __launch_bounds__(256,3) void gemm_expert(
    const u16* __restrict__ Abf, const u16* __restrict__ ewh,
    const float* __restrict__ eb, const int* __restrict__ list,
    const int* __restrict__ counts, const float* __restrict__ gval,
    u16* __restrict__ sel)
{
    const int lin = blockIdx.x + (blockIdx.y << 3) + (blockIdx.z << 8); // 0..2047
    const int n0 = (lin & 7) * 128;
    const int idx = lin >> 3;            // 0..255 within XCD
    const int e   = idx >> 5;            // expert, panel-serial within XCD
    const int m0  = (idx & 31) * 128;
    const int cnt = counts[e];
    if (m0 >= cnt) return;
    __shared__ __align__(16) u16 sA[2][128*32], sB[2][128*32];
    __shared__ int sEnt[128];
    const int t = threadIdx.x;
    if (t < 128) sEnt[t] = (m0 + t < cnt) ? list[e * TOKENS + m0 + t] : -1;
    __syncthreads();
    const int lane = t & 63, w = t >> 6;
    const int wm = w >> 1, wn = w & 1;
    const int lr = lane & 15, qd = lane >> 4;
    const int e0 = sEnt[t >> 2], e1 = sEnt[64 + (t >> 2)];
    const u16* ga0 = Abf + (size_t)(e0 < 0 ? 0 : (e0 >> 1)) * E_ + (t & 3) * 8;
    const u16* ga1 = Abf + (size_t)(e1 < 0 ? 0 : (e1 >> 1)) * E_ + (t & 3) * 8;
    const u16* gb0 = ewh + (size_t)e * E_ * E_ + (size_t)(n0 + (t >> 2)) * E_ + (t & 3) * 8;
    const u16* gb1 = gb0 + 64 * E_;
    f32x4 acc[4][4] = {};
    for (int k0 = 0; k0 < E_; k0 += 64) {
        #pragma unroll
        for (int half = 0; half < 2; half++) {
            const int l0 = (t & 192) * 16;
            const int l1 = (256 + (t & 192)) * 16;
            const int kk = k0 + half*32;
            gl2lds16(ga0 + kk, (char*)sA[half] + l0);
            gl2lds16(ga1 + kk, (char*)sA[half] + l1);
            gl2lds16(gb0 + kk, (char*)sB[half] + l0);
            gl2lds16(gb1 + kk, (char*)sB[half] + l1);
        }
        __syncthreads();
        #pragma unroll
        for (int half = 0; half < 2; half++) {
            bf16x8 af[4], bfr[4];
            #pragma unroll
            for (int i = 0; i < 4; i++) {
                af[i]  = *(const bf16x8*)&sA[half][(wm*64 + i*16 + lr)*32 + qd*8];
                bfr[i] = *(const bf16x8*)&sB[half][(wn*64 + i*16 + lr)*32 + qd*8];
            }
            #pragma unroll
            for (int i = 0; i < 4; i++)
                #pragma unroll
                for (int j = 0; j < 4; j++)
                    acc[i][j] = MFMA16(af[i], bfr[j], acc[i][j]);
        }
        __syncthreads();
    }
    #pragma unroll
    for (int i = 0; i < 4; i++)
        #pragma unroll
        for (int r = 0; r < 4; r++) {
            const int local = wm*64 + i*16 + qd*4 + r;
            const int ent = sEnt[local];
            if (ent < 0) continue;
            const float g = gval[ent];
            #pragma unroll
            for (int j = 0; j < 4; j++) {
                const int col = n0 + wn*64 + j*16 + lr;
                sel[(size_t)ent * E_ + col] = f2bf((acc[i][j][r] + eb[e * E_ + col]) * g);
            }
        }
}

// ---------------------------------------------------------------------------
// moe[tok] = sel[tok*2] + sel[tok*2+1]  (bf16 in/out)
// ---------------------------------------------------------------------------
__global__ void combine_kernel(const u16* __restrict__ sel, u16* __restrict__ moe)
{
    const int g = blockIdx.x * 256 + threadIdx.x;
    const int tok = g >> 8;
    const int c = (g & 255) * 4;
    const u16* a = sel + (size_t)tok * 2048 + c;
    float o[4];
    #pragma unroll
    for (int j = 0; j < 4; j++) o[j] = bf2f(a[j]) + bf2f(a[1024 + j]);
    ushort4 R = {f2bf(o[0]), f2bf(o[1]), f2bf(o[2]), f2bf(o[3])};
    *(ushort4*)(moe + (size_t)tok * E_ + c) = R;
}

// ---------------------------------------------------------------------------
// FFN GEMM (bf16) + bias + fp32 residual -> fp32 out.
// 128x64 tiles -> 512 blocks @3/CU (full device). BK=64 paired half tiles;
// XCD swizzle: each XCD owns n-tiles {x, x+8}.
// ---------------------------------------------------------------------------
__global__ __launch_bounds__(256,3) void gemm_ffn(
    const u16* __restrict__ Ah, const u16* __restrict__ Bh,
    const float* __restrict__ bias, const float* __restrict__ res,
    float* __restrict__ C)
{
    __shared__ __align__(16) u16 sA[2][128*32], sB[2][64*32];
    const int t = threadIdx.x;
    const int lin = blockIdx.x + (blockIdx.y << 4);   // 0..511
    const int idx = lin >> 3;                          // 0..63 within XCD
    const int m0 = (idx & 31) * 128;
    const int n0 = ((idx >> 5) * 8 + (lin & 7)) * 64;  // n-tile 0..15
    const int lane = t & 63, w = t >> 6;
    const int wm = w >> 1, wn = w & 1;
    const int lr = lane & 15, qd = lane >> 4;
    f32x4 acc[4][2] = {};
    const size_t gA = (size_t)(m0 + (t >> 2)) * E_ + (t & 3) * 8;
    const size_t gB = (size_t)(n0 + (t >> 2)) * E_ + (t & 3) * 8;
    for (int k0 = 0; k0 < E_; k0 += 64) {
        #pragma unroll
        for (int half = 0; half < 2; half++) {
            const int kk = k0 + half*32;
            #pragma unroll
            for (int is = 0; is < 2; is++) {
                const int ldo = (is * 256 + (t & 192)) * 16;
                const size_t ro = (size_t)is * 64 * E_;
                gl2lds16(Ah + gA + ro + kk, (char*)sA[half] + ldo);
            }
            gl2lds16(Bh + gB + kk, (char*)sB[half] + t*16);   // 64 rows x 32 cols
        }
        __syncthreads();
        #pragma unroll
        for (int half = 0; half < 2; half++) {
            bf16x8 af[4], bfr[2];
            #pragma unroll
            for (int i = 0; i < 4; i++)
                af[i] = *(const bf16x8*)&sA[half][(wm*64 + i*16 + lr)*32 + qd*8];
            #pragma unroll
            for (int j = 0; j < 2; j++)
                bfr[j] = *(const bf16x8*)&sB[half][(wn*32 + j*16 + lr)*32 + qd*8];
            #pragma unroll
            for (int i = 0; i < 4; i++)
                #pragma unroll
                for (int j = 0; j < 2; j++)
                    acc[i][j] = MFMA16(af[i], bfr[j], acc[i][j]);
        }
        __syncthreads();
    }
    #pragma unroll
    for (int i = 0; i < 4; i++)
        #pragma unroll
        for (int r = 0; r < 4; r++) {
            const int tok = m0 + wm*64 + i*16 + qd*4 + r;
            #pragma unroll
            for (int j = 0; j < 2; j++) {
                const int col = n0 + wn*32 + j*16 + lr;
                C[(size_t)tok * E_ + col] = acc[i][j][r] + bias[col] + res[(size_t)tok * E_ + col];
            }
        }
}

// ---------------------------------------------------------------------------
extern "C" void kernel_launch(void* const* d_in, const int* in_sizes, int n_in,
                              void* d_out, int out_size, void* d_ws, size_t ws_size,
                              hipStream_t stream) {
    const float* x      = (const float*)d_in[0];
    const float* q_w    = (const float*)d_in[1];
    const float* q_b    = (const float*)d_in[2];
    const float* k_w    = (const float*)d_in[3];
    const float* k_b    = (const float*)d_in[4];
    const float* v_w    = (const float*)d_in[5];
    const float* v_b    = (const float*)d_in[6];
    const float* gate_w = (const float*)d_in[7];
    const float* gate_b = (const float*)d_in[8];
    const float* ew     = (const float*)d_in[9];
    const float* eb     = (const float*)d_in[10];
    const float* ffn_w  = (const float*)d_in[11];
    const float* ffn_b  = (const float*)d_in[12];
    float* out = (float*)d_out;

    char* p = (char*)d_ws;
    auto alloc = [&](size_t bytes) { char* r = p; p += (bytes + 255) & ~(size_t)255; return r; };
    u16* xh   = (u16*)alloc((size_t)TOKENS*E_*2);
    u16* qwh  = (u16*)alloc((size_t)E_*E_*2);
    u16* kwh  = (u16*)alloc((size_t)E_*E_*2);
    u16* vwh  = (u16*)alloc((size_t)E_*E_*2);
    u16* fwh  = (u16*)alloc((size_t)E_*E_*2);
    u16* ewh  = (u16*)alloc((size_t)NE_*E_*E_*2);
    u16* Qhb  = (u16*)alloc((size_t)TOKENS*E_*2);
    u16* Khb  = (u16*)alloc((size_t)TOKENS*E_*2);
    u16* Vtb  = (u16*)alloc((size_t)TOKENS*E_*2);
    u16* abf  = (u16*)alloc((size_t)TOKENS*E_*2);
    u16* Opart = (u16*)alloc((size_t)2*TOKENS*E_*2);
    float* lpart = (float*)alloc((size_t)2*TOKENS*H_*4);
    u16* selb = (u16*)alloc((size_t)2*TOKENS*E_*2);
    u16* moeb = (u16*)alloc((size_t)TOKENS*E_*2);
    float2* rtab = (float2*)alloc((size_t)S_*32*8);
    float* gvl = (float*)alloc((size_t)2*TOKENS*4);
    int*   eix = (int*)alloc((size_t)2*TOKENS*4);
    int*   lst = (int*)alloc((size_t)NE_*TOKENS*4);
    int*   cnt = (int*)alloc(256);

    hipMemsetAsync(cnt, 0, 256, stream);

    cvt_all_k<<<16640, 256, 0, stream>>>(x, q_w, k_w, v_w, ffn_w, ew,
                                         xh, qwh, kwh, vwh, fwh, ewh, rtab);

    gemm_qkv<<<dim3(8,32,3), 256, 0, stream>>>(xh, qwh, kwh, vwh,
                                               q_b, k_b, v_b, rtab,
                                               Qhb, Khb, Vtb);

    attn_kernel<<<dim3(16,16,4), 256, 0, stream>>>(Qhb, Khb, Vtb, Opart, lpart);

    combine_gate<<<TOKENS/4, 256, 0, stream>>>(Opart, lpart, gate_w, gate_b,
                                               abf, gvl, eix);
    build_lists_kernel<<<TOKENS/256, 256, 0, stream>>>(eix, lst, cnt);
    gemm_expert<<<dim3(8,32,8), 256, 0, stream>>>(abf, ewh, eb, lst, cnt, gvl, selb);
    combine_kernel<<<4096, 256, 0, stream>>>(selb, moeb);
    gemm_ffn<<<dim3(16,32), 256, 0, stream>>>(moeb, fwh, ffn_b, x, out);
}